// Round 1
// baseline (54454.950 us; speedup 1.0000x reference)
//
#include <hip/hip_runtime.h>
#include <hip/hip_bf16.h>

// Problem constants (from reference)
#define TSEQ 65536
#define INPUT_SIZE 128
#define HIDDEN 100
#define GATES 400   // 4*HIDDEN

__device__ __forceinline__ float fast_sigmoid(float x) {
    return 1.0f / (1.0f + __expf(-x));
}
__device__ __forceinline__ float fast_tanh(float x) {
    // robust at +-inf: exp(2x)->inf => 1; exp(2x)->0 => -1
    return 1.0f - 2.0f / (__expf(2.0f * x) + 1.0f);
}

// ---------------------------------------------------------------------------
// Kernel 1: xp[t][j] = b_ih[j] + b_hh[j] + sum_k x[t][k] * W_ih[j][k]
// Block: 256 threads, handles 16 timesteps. Grid: TSEQ/16 = 4096 blocks.
// ---------------------------------------------------------------------------
__global__ __launch_bounds__(256) void xproj_kernel(
    const float* __restrict__ x,     // [TSEQ][128]
    const float* __restrict__ W,     // [400][128]
    const float* __restrict__ bi,    // [400]
    const float* __restrict__ bh,    // [400]
    float* __restrict__ xp)          // [TSEQ][400]
{
    __shared__ __align__(16) float xs[16 * 128];
    const int tid = threadIdx.x;
    const int t0 = blockIdx.x * 16;

    // stage 16 x-rows (2048 floats) coalesced
#pragma unroll
    for (int i = 0; i < 8; ++i)
        xs[i * 256 + tid] = x[(size_t)t0 * 128 + i * 256 + tid];
    __syncthreads();

    const int j1 = tid;            // always < 400
    const int j2 = tid + 256;      // valid if < 400
    const bool has2 = (j2 < GATES);

    float acc1[16], acc2[16];
    const float bias1 = bi[j1] + bh[j1];
    const float bias2 = has2 ? (bi[j2] + bh[j2]) : 0.0f;
#pragma unroll
    for (int tt = 0; tt < 16; ++tt) { acc1[tt] = bias1; acc2[tt] = bias2; }

    const float4* W4 = reinterpret_cast<const float4*>(W);
    const float4* xs4 = reinterpret_cast<const float4*>(xs);

    for (int kk = 0; kk < 32; ++kk) {               // 128 k in float4 chunks
        const float4 wa = W4[(size_t)j1 * 32 + kk];
        float4 wb = make_float4(0.f, 0.f, 0.f, 0.f);
        if (has2) wb = W4[(size_t)j2 * 32 + kk];
#pragma unroll
        for (int tt = 0; tt < 16; ++tt) {
            const float4 xv = xs4[tt * 32 + kk];    // LDS broadcast
            acc1[tt] = fmaf(wa.x, xv.x, acc1[tt]);
            acc1[tt] = fmaf(wa.y, xv.y, acc1[tt]);
            acc1[tt] = fmaf(wa.z, xv.z, acc1[tt]);
            acc1[tt] = fmaf(wa.w, xv.w, acc1[tt]);
            acc2[tt] = fmaf(wb.x, xv.x, acc2[tt]);
            acc2[tt] = fmaf(wb.y, xv.y, acc2[tt]);
            acc2[tt] = fmaf(wb.z, xv.z, acc2[tt]);
            acc2[tt] = fmaf(wb.w, xv.w, acc2[tt]);
        }
    }

#pragma unroll
    for (int tt = 0; tt < 16; ++tt) {
        xp[(size_t)(t0 + tt) * GATES + j1] = acc1[tt];
        if (has2) xp[(size_t)(t0 + tt) * GATES + j2] = acc2[tt];
    }
}

// ---------------------------------------------------------------------------
// Kernel 2: the sequential LSTM recurrence. ONE block, 512 threads (8 waves).
// Threads 0..399 each own one gate row of W_hh (100 floats in VGPRs).
// h broadcast via LDS; c resident in registers of threads 0..99.
// xp prefetched 4 steps deep (rotating register buffer, unroll-by-4).
// ---------------------------------------------------------------------------
__global__ __launch_bounds__(512, 1) void lstm_rec_kernel(
    const float* __restrict__ xp,    // [TSEQ][400] (includes both biases)
    const float* __restrict__ Whh,   // [400][100]
    float* __restrict__ hs)          // [TSEQ][100]
{
    __shared__ __align__(16) float h_lds[HIDDEN];     // 100 floats, 25 float4
    __shared__ __align__(16) float gates_lds[GATES];

    const int tid = threadIdx.x;
    const bool gate_thread = (tid < GATES);
    const bool cell_thread = (tid < HIDDEN);

    // W_hh row -> registers (25 float4 = 100 VGPRs), static indexing only
    float4 wv[25];
    if (gate_thread) {
        const float4* wrow = reinterpret_cast<const float4*>(Whh + (size_t)tid * HIDDEN);
#pragma unroll
        for (int kk = 0; kk < 25; ++kk) wv[kk] = wrow[kk];
    } else {
#pragma unroll
        for (int kk = 0; kk < 25; ++kk) wv[kk] = make_float4(0.f, 0.f, 0.f, 0.f);
    }

    if (cell_thread) h_lds[tid] = 0.0f;
    float c = 0.0f;

    // gate selector: 0=i 1=f 2=g 3=o
    const int gsel = tid / HIDDEN;

    // depth-4 xp prefetch
    float xpv[4];
    if (gate_thread) {
#pragma unroll
        for (int p = 0; p < 4; ++p) xpv[p] = xp[(size_t)p * GATES + tid];
    }
    __syncthreads();

    const float4* h4 = reinterpret_cast<const float4*>(h_lds);

    for (int t = 0; t < TSEQ; t += 4) {
#pragma unroll
        for (int u = 0; u < 4; ++u) {
            const int tt = t + u;
            if (gate_thread) {
                float acc = xpv[u];
#pragma unroll
                for (int kk = 0; kk < 25; ++kk) {
                    const float4 hv = h4[kk];      // LDS broadcast read
                    acc = fmaf(wv[kk].x, hv.x, acc);
                    acc = fmaf(wv[kk].y, hv.y, acc);
                    acc = fmaf(wv[kk].z, hv.z, acc);
                    acc = fmaf(wv[kk].w, hv.w, acc);
                }
                // prefetch xp for step tt+4 (used 4 iterations from now)
                if (tt + 4 < TSEQ) xpv[u] = xp[(size_t)(tt + 4) * GATES + tid];
                gates_lds[tid] = (gsel == 2) ? fast_tanh(acc) : fast_sigmoid(acc);
            }
            __syncthreads();   // gates ready; also: all h reads for step tt done
            if (cell_thread) {
                const float gi = gates_lds[tid];
                const float gf = gates_lds[tid + HIDDEN];
                const float gg = gates_lds[tid + 2 * HIDDEN];
                const float go = gates_lds[tid + 3 * HIDDEN];
                c = fmaf(gf, c, gi * gg);
                const float hval = go * fast_tanh(c);
                h_lds[tid] = hval;
                hs[(size_t)tt * HIDDEN + tid] = hval;   // fire-and-forget
            }
            __syncthreads();   // new h visible to all before next step
        }
    }
}

// ---------------------------------------------------------------------------
// Kernel 3: out[t] = sigmoid(dot(hs[t], W_lin) + b_lin)
// ---------------------------------------------------------------------------
__global__ __launch_bounds__(256) void pred_kernel(
    const float* __restrict__ hs,     // [TSEQ][100]
    const float* __restrict__ wlin,   // [100]
    const float* __restrict__ blin,   // [1]
    float* __restrict__ out)          // [TSEQ]
{
    __shared__ __align__(16) float wl[HIDDEN];
    const int tid = threadIdx.x;
    if (tid < HIDDEN) wl[tid] = wlin[tid];
    __syncthreads();

    const int t = blockIdx.x * 256 + tid;
    const float4* h4 = reinterpret_cast<const float4*>(hs + (size_t)t * HIDDEN);
    const float4* w4 = reinterpret_cast<const float4*>(wl);
    float acc = blin[0];
#pragma unroll
    for (int kk = 0; kk < 25; ++kk) {
        const float4 hv = h4[kk];
        const float4 wv = w4[kk];
        acc = fmaf(hv.x, wv.x, acc);
        acc = fmaf(hv.y, wv.y, acc);
        acc = fmaf(hv.z, wv.z, acc);
        acc = fmaf(hv.w, wv.w, acc);
    }
    out[t] = fast_sigmoid(acc);
}

// ---------------------------------------------------------------------------
extern "C" void kernel_launch(void* const* d_in, const int* in_sizes, int n_in,
                              void* d_out, int out_size, void* d_ws, size_t ws_size,
                              hipStream_t stream) {
    const float* x     = (const float*)d_in[0];  // [65536,128]
    const float* W_ih  = (const float*)d_in[1];  // [400,128]
    const float* W_hh  = (const float*)d_in[2];  // [400,100]
    const float* b_ih  = (const float*)d_in[3];  // [400]
    const float* b_hh  = (const float*)d_in[4];  // [400]
    const float* W_lin = (const float*)d_in[5];  // [1,100]
    const float* b_lin = (const float*)d_in[6];  // [1]
    float* out = (float*)d_out;                  // [65536]

    // workspace layout: xp [TSEQ*400] fp32, then hs [TSEQ*100] fp32 (131 MB)
    float* xp = (float*)d_ws;
    float* hs = xp + (size_t)TSEQ * GATES;

    xproj_kernel<<<TSEQ / 16, 256, 0, stream>>>(x, W_ih, b_ih, b_hh, xp);
    lstm_rec_kernel<<<1, 512, 0, stream>>>(xp, W_hh, hs);
    pred_kernel<<<TSEQ / 256, 256, 0, stream>>>(hs, W_lin, b_lin, out);
}

// Round 2
// 36027.795 us; speedup vs baseline: 1.5115x; 1.5115x over previous
//
#include <hip/hip_runtime.h>
#include <hip/hip_bf16.h>

#define TSEQ 65536
#define INPUT_SIZE 128
#define HIDDEN 100
#define GATES 400   // 4*HIDDEN

typedef __attribute__((ext_vector_type(8))) short bf16x8;
typedef __attribute__((ext_vector_type(4))) float f32x4;

__device__ __forceinline__ unsigned short f2bf(float x) {
    union { float f; unsigned int u; } v; v.f = x;
    unsigned int r = v.u + 0x7fffu + ((v.u >> 16) & 1u);
    return (unsigned short)(r >> 16);
}
__device__ __forceinline__ float rcp_fast(float x) { return __builtin_amdgcn_rcpf(x); }
__device__ __forceinline__ float sigm(float x) { return rcp_fast(1.0f + __expf(-x)); }
__device__ __forceinline__ float tanh_fast(float x) {
    return 1.0f - 2.0f * rcp_fast(__expf(2.0f * x) + 1.0f);
}

// barrier without vmcnt drain: LDS-drain + s_barrier + compiler memory fence
#define LDS_BARRIER()                                              \
    do {                                                           \
        asm volatile("s_waitcnt lgkmcnt(0)" ::: "memory");         \
        __builtin_amdgcn_s_barrier();                              \
        asm volatile("" ::: "memory");                             \
    } while (0)

// ---------------------------------------------------------------------------
// Kernel 1: xp_perm[t][4*u + g] = b_ih[j] + b_hh[j] + sum_k x[t][k]*W_ih[j][k]
// where j = g*100 + u (original gate row). Unit-major/gate-minor layout so the
// recurrence reads each unit's 4 gate pre-activations as one float4.
// ---------------------------------------------------------------------------
__global__ __launch_bounds__(256) void xproj_kernel(
    const float* __restrict__ x,     // [TSEQ][128]
    const float* __restrict__ W,     // [400][128]
    const float* __restrict__ bi,    // [400]
    const float* __restrict__ bh,    // [400]
    float* __restrict__ xp)          // [TSEQ][400] (permuted)
{
    __shared__ __align__(16) float xs[16 * 128];
    const int tid = threadIdx.x;
    const int t0 = blockIdx.x * 16;

#pragma unroll
    for (int i = 0; i < 8; ++i)
        xs[i * 256 + tid] = x[(size_t)t0 * 128 + i * 256 + tid];
    __syncthreads();

    const int j1 = tid;
    const int j2 = tid + 256;
    const bool has2 = (j2 < GATES);
    const int p1 = 4 * (j1 % 100) + (j1 / 100);            // permuted index
    const int p2 = has2 ? (4 * (j2 % 100) + (j2 / 100)) : 0;

    float acc1[16], acc2[16];
    const float bias1 = bi[j1] + bh[j1];
    const float bias2 = has2 ? (bi[j2] + bh[j2]) : 0.0f;
#pragma unroll
    for (int tt = 0; tt < 16; ++tt) { acc1[tt] = bias1; acc2[tt] = bias2; }

    const float4* W4 = reinterpret_cast<const float4*>(W);
    const float4* xs4 = reinterpret_cast<const float4*>(xs);

    for (int kk = 0; kk < 32; ++kk) {
        const float4 wa = W4[(size_t)j1 * 32 + kk];
        float4 wb = make_float4(0.f, 0.f, 0.f, 0.f);
        if (has2) wb = W4[(size_t)j2 * 32 + kk];
#pragma unroll
        for (int tt = 0; tt < 16; ++tt) {
            const float4 xv = xs4[tt * 32 + kk];
            acc1[tt] = fmaf(wa.x, xv.x, acc1[tt]);
            acc1[tt] = fmaf(wa.y, xv.y, acc1[tt]);
            acc1[tt] = fmaf(wa.z, xv.z, acc1[tt]);
            acc1[tt] = fmaf(wa.w, xv.w, acc1[tt]);
            acc2[tt] = fmaf(wb.x, xv.x, acc2[tt]);
            acc2[tt] = fmaf(wb.y, xv.y, acc2[tt]);
            acc2[tt] = fmaf(wb.z, xv.z, acc2[tt]);
            acc2[tt] = fmaf(wb.w, xv.w, acc2[tt]);
        }
    }

#pragma unroll
    for (int tt = 0; tt < 16; ++tt) {
        xp[(size_t)(t0 + tt) * GATES + p1] = acc1[tt];
        if (has2) xp[(size_t)(t0 + tt) * GATES + p2] = acc2[tt];
    }
}

// ---------------------------------------------------------------------------
// Kernel 2: LSTM recurrence, one block, 256 threads (4 waves).
// Phase A: 25 row-tiles of mfma_f32_16x16x32_bf16 (W_hh row-permuted so tile
//          rows 4q..4q+3 are the 4 gates of hidden unit 4*tile+q). B operand =
//          bf16 h replicated in all 16 columns (16B LDS broadcast per lane).
//          Col-0 lanes ds_write_b128 raw pre-activations to LDS.
// Phase B: threads 0..99 do activations + cell update, write bf16 h back.
// NOTE: no __restrict__ on pointers — hs stores alias-block the compiler from
// rematerializing the A-fragment weight loads inside the loop (R1 failure).
// ---------------------------------------------------------------------------
__global__ __launch_bounds__(256, 1) void lstm_rec_kernel(
    const float* xp,     // [TSEQ][400] permuted, includes biases
    const float* Whh,    // [400][100] original layout
    float* hs)           // [TSEQ][100]
{
    __shared__ __align__(16) unsigned short h_lds[2][128];  // bf16 h, zero-padded
    __shared__ __align__(16) float preact_lds[GATES];       // permuted pre-acts

    const int tid = threadIdx.x;
    const int lane = tid & 63;
    const int w = tid >> 6;          // wave 0..3
    const int bq = lane >> 4;        // k-block 0..3 within fragment
    const int m = lane & 15;         // A row within tile / D col
    const bool writer = (m == 0);    // D col 0 holds the (replicated) result

    // ---- A fragments: 7 tile-slots (wave w: tiles 6w..6w+5; slot 6 = tile 24, wave 3 only)
    bf16x8 afrag[7][4];
#pragma unroll
    for (int i = 0; i < 7; ++i) {
        const int ti = (i < 6) ? (6 * w + i) : 24;
        const bool valid = (i < 6) || (w == 3);
        // permuted tile-row m -> original W_hh row
        const int g = m & 3;
        const int uu = 4 * ti + (m >> 2);
        const int orow = g * 100 + uu;
#pragma unroll
        for (int kk = 0; kk < 4; ++kk) {
            float vals[8];
            if (valid && kk < 3) {
                const float4 w0 = *(const float4*)&Whh[(size_t)orow * 100 + kk * 32 + bq * 8];
                const float4 w1 = *(const float4*)&Whh[(size_t)orow * 100 + kk * 32 + bq * 8 + 4];
                vals[0] = w0.x; vals[1] = w0.y; vals[2] = w0.z; vals[3] = w0.w;
                vals[4] = w1.x; vals[5] = w1.y; vals[6] = w1.z; vals[7] = w1.w;
            } else if (valid && bq == 0) {       // kk==3, k = 96..103: only 96..99 real
                const float4 w0 = *(const float4*)&Whh[(size_t)orow * 100 + 96];
                vals[0] = w0.x; vals[1] = w0.y; vals[2] = w0.z; vals[3] = w0.w;
                vals[4] = 0.f; vals[5] = 0.f; vals[6] = 0.f; vals[7] = 0.f;
            } else {
#pragma unroll
                for (int j = 0; j < 8; ++j) vals[j] = 0.f;
            }
#pragma unroll
            for (int j = 0; j < 8; ++j) afrag[i][kk][j] = (short)f2bf(vals[j]);
        }
    }

    // ---- init: h = 0 (both buffers, incl. zero K-padding), c = 0, xp prefetch
    if (tid < 128) { h_lds[0][tid] = 0; h_lds[1][tid] = 0; }
    float c = 0.0f;
    float4 xpv[4];
    if (tid < HIDDEN) {
#pragma unroll
        for (int p = 0; p < 4; ++p)
            xpv[p] = *(const float4*)&xp[(size_t)p * GATES + 4 * tid];
    }
    __syncthreads();

    for (int t = 0; t < TSEQ; t += 4) {
#pragma unroll
        for (int u = 0; u < 4; ++u) {
            const int tt = t + u;
            const int cur = u & 1;   // t % 4 == 0, so parity of tt == parity of u

            // ---- Phase A: B fragments (h broadcast) + MFMA
            bf16x8 bf[4];
#pragma unroll
            for (int kk = 0; kk < 4; ++kk) {
                const uint4 braw = *(const uint4*)&h_lds[cur][kk * 32 + bq * 8];
                bf[kk] = __builtin_bit_cast(bf16x8, braw);
            }
#pragma unroll
            for (int i = 0; i < 7; ++i) {
                const bool valid = (i < 6) || (w == 3);
                if (valid) {
                    const int ti = (i < 6) ? (6 * w + i) : 24;
                    f32x4 acc = {0.f, 0.f, 0.f, 0.f};
                    acc = __builtin_amdgcn_mfma_f32_16x16x32_bf16(afrag[i][0], bf[0], acc, 0, 0, 0);
                    acc = __builtin_amdgcn_mfma_f32_16x16x32_bf16(afrag[i][1], bf[1], acc, 0, 0, 0);
                    acc = __builtin_amdgcn_mfma_f32_16x16x32_bf16(afrag[i][2], bf[2], acc, 0, 0, 0);
                    acc = __builtin_amdgcn_mfma_f32_16x16x32_bf16(afrag[i][3], bf[3], acc, 0, 0, 0);
                    if (writer)   // rows 4*bq..4*bq+3 of tile ti -> permuted gate idx
                        *(f32x4*)&preact_lds[16 * ti + 4 * bq] = acc;
                }
            }
            LDS_BARRIER();   // pre-acts visible; all h reads of this step done

            // ---- Phase B: cell update (threads 0..99, unit = tid)
            if (tid < HIDDEN) {
                const float4 pa = *(const float4*)&preact_lds[4 * tid];
                const float4 xq = xpv[u];
                const float gi = sigm(pa.x + xq.x);
                const float gf = sigm(pa.y + xq.y);
                const float gg = tanh_fast(pa.z + xq.z);
                const float go = sigm(pa.w + xq.w);
                c = fmaf(gf, c, gi * gg);
                const float hv = go * tanh_fast(c);
                hs[(size_t)tt * HIDDEN + tid] = hv;          // fire-and-forget
                h_lds[1 - cur][tid] = f2bf(hv);
                if (tt + 4 < TSEQ)                            // depth-4 prefetch
                    xpv[u] = *(const float4*)&xp[(size_t)(tt + 4) * GATES + 4 * tid];
            }
            LDS_BARRIER();   // new h visible; preact reads done -> safe to overwrite
        }
    }
}

// ---------------------------------------------------------------------------
// Kernel 3: out[t] = sigmoid(dot(hs[t], W_lin) + b_lin)
// ---------------------------------------------------------------------------
__global__ __launch_bounds__(256) void pred_kernel(
    const float* __restrict__ hs,     // [TSEQ][100]
    const float* __restrict__ wlin,   // [100]
    const float* __restrict__ blin,   // [1]
    float* __restrict__ out)          // [TSEQ]
{
    __shared__ __align__(16) float wl[HIDDEN];
    const int tid = threadIdx.x;
    if (tid < HIDDEN) wl[tid] = wlin[tid];
    __syncthreads();

    const int t = blockIdx.x * 256 + tid;
    const float4* h4 = reinterpret_cast<const float4*>(hs + (size_t)t * HIDDEN);
    const float4* w4 = reinterpret_cast<const float4*>(wl);
    float acc = blin[0];
#pragma unroll
    for (int kk = 0; kk < 25; ++kk) {
        const float4 hv = h4[kk];
        const float4 wv = w4[kk];
        acc = fmaf(hv.x, wv.x, acc);
        acc = fmaf(hv.y, wv.y, acc);
        acc = fmaf(hv.z, wv.z, acc);
        acc = fmaf(hv.w, wv.w, acc);
    }
    out[t] = sigm(acc);
}

// ---------------------------------------------------------------------------
extern "C" void kernel_launch(void* const* d_in, const int* in_sizes, int n_in,
                              void* d_out, int out_size, void* d_ws, size_t ws_size,
                              hipStream_t stream) {
    const float* x     = (const float*)d_in[0];  // [65536,128]
    const float* W_ih  = (const float*)d_in[1];  // [400,128]
    const float* W_hh  = (const float*)d_in[2];  // [400,100]
    const float* b_ih  = (const float*)d_in[3];  // [400]
    const float* b_hh  = (const float*)d_in[4];  // [400]
    const float* W_lin = (const float*)d_in[5];  // [1,100]
    const float* b_lin = (const float*)d_in[6];  // [1]
    float* out = (float*)d_out;                  // [65536]

    float* xp = (float*)d_ws;                        // [TSEQ*400] fp32 (permuted)
    float* hs = xp + (size_t)TSEQ * GATES;           // [TSEQ*100] fp32

    xproj_kernel<<<TSEQ / 16, 256, 0, stream>>>(x, W_ih, b_ih, b_hh, xp);
    lstm_rec_kernel<<<1, 256, 0, stream>>>(xp, W_hh, hs);
    pred_kernel<<<TSEQ / 256, 256, 0, stream>>>(hs, W_lin, b_lin, out);
}

// Round 3
// 32845.749 us; speedup vs baseline: 1.6579x; 1.0969x over previous
//
#include <hip/hip_runtime.h>
#include <hip/hip_bf16.h>

#define TSEQ 65536
#define INPUT_SIZE 128
#define HIDDEN 100
#define GATES 400   // 4*HIDDEN

typedef __attribute__((ext_vector_type(8))) short bf16x8;
typedef __attribute__((ext_vector_type(4))) float f32x4;

__device__ __forceinline__ unsigned short f2bf(float x) {
    union { float f; unsigned int u; } v; v.f = x;
    unsigned int r = v.u + 0x7fffu + ((v.u >> 16) & 1u);
    return (unsigned short)(r >> 16);
}
__device__ __forceinline__ float bf2f(unsigned int u) {
    union { unsigned int u; float f; } v; v.u = u << 16; return v.f;
}
__device__ __forceinline__ float rcp_fast(float x) { return __builtin_amdgcn_rcpf(x); }
__device__ __forceinline__ float sigm(float x) { return rcp_fast(1.0f + __expf(-x)); }
__device__ __forceinline__ float tanh_fast(float x) {
    return 1.0f - 2.0f * rcp_fast(__expf(2.0f * x) + 1.0f);
}

// barrier without vmcnt drain: LDS-drain + s_barrier + compiler memory fence
#define LDS_BARRIER()                                              \
    do {                                                           \
        asm volatile("s_waitcnt lgkmcnt(0)" ::: "memory");         \
        __builtin_amdgcn_s_barrier();                              \
        asm volatile("" ::: "memory");                             \
    } while (0)

// ---------------------------------------------------------------------------
// Kernel 1: xp_perm[t][4*u + g] = b_ih[j] + b_hh[j] + sum_k x[t][k]*W_ih[j][k]
// where j = g*100 + u (original gate row). Unit-major/gate-minor layout.
// ---------------------------------------------------------------------------
__global__ __launch_bounds__(256) void xproj_kernel(
    const float* __restrict__ x,     // [TSEQ][128]
    const float* __restrict__ W,     // [400][128]
    const float* __restrict__ bi,    // [400]
    const float* __restrict__ bh,    // [400]
    float* __restrict__ xp)          // [TSEQ][400] (permuted)
{
    __shared__ __align__(16) float xs[16 * 128];
    const int tid = threadIdx.x;
    const int t0 = blockIdx.x * 16;

#pragma unroll
    for (int i = 0; i < 8; ++i)
        xs[i * 256 + tid] = x[(size_t)t0 * 128 + i * 256 + tid];
    __syncthreads();

    const int j1 = tid;
    const int j2 = tid + 256;
    const bool has2 = (j2 < GATES);
    const int p1 = 4 * (j1 % 100) + (j1 / 100);
    const int p2 = has2 ? (4 * (j2 % 100) + (j2 / 100)) : 0;

    float acc1[16], acc2[16];
    const float bias1 = bi[j1] + bh[j1];
    const float bias2 = has2 ? (bi[j2] + bh[j2]) : 0.0f;
#pragma unroll
    for (int tt = 0; tt < 16; ++tt) { acc1[tt] = bias1; acc2[tt] = bias2; }

    const float4* W4 = reinterpret_cast<const float4*>(W);
    const float4* xs4 = reinterpret_cast<const float4*>(xs);

    for (int kk = 0; kk < 32; ++kk) {
        const float4 wa = W4[(size_t)j1 * 32 + kk];
        float4 wb = make_float4(0.f, 0.f, 0.f, 0.f);
        if (has2) wb = W4[(size_t)j2 * 32 + kk];
#pragma unroll
        for (int tt = 0; tt < 16; ++tt) {
            const float4 xv = xs4[tt * 32 + kk];
            acc1[tt] = fmaf(wa.x, xv.x, acc1[tt]);
            acc1[tt] = fmaf(wa.y, xv.y, acc1[tt]);
            acc1[tt] = fmaf(wa.z, xv.z, acc1[tt]);
            acc1[tt] = fmaf(wa.w, xv.w, acc1[tt]);
            acc2[tt] = fmaf(wb.x, xv.x, acc2[tt]);
            acc2[tt] = fmaf(wb.y, xv.y, acc2[tt]);
            acc2[tt] = fmaf(wb.z, xv.z, acc2[tt]);
            acc2[tt] = fmaf(wb.w, xv.w, acc2[tt]);
        }
    }

#pragma unroll
    for (int tt = 0; tt < 16; ++tt) {
        xp[(size_t)(t0 + tt) * GATES + p1] = acc1[tt];
        if (has2) xp[(size_t)(t0 + tt) * GATES + p2] = acc2[tt];
    }
}

// ---------------------------------------------------------------------------
// Kernel 2: LSTM recurrence, one block, 256 threads (4 waves), ONE barrier/step.
// Wave w owns tiles 6w..6w+5 (w3 also tile 24) -> units 24w..24w+23 (w3 +96..99).
// MFMA writer lanes (m==0, bq) ds_write the f32x4 preact of unit 4*ti+bq;
// the SAME wave's lanes 0..23 (w3 0..27) ds_read their own unit's preact
// (intra-wave LDS is in-order -> no barrier), do the cell update, write bf16 h.
// Single s_barrier publishes h to all waves. hs output stored as bf16.
// NOTE: no __restrict__ -> hs stores alias-block W_hh load rematerialization.
// ---------------------------------------------------------------------------
__global__ __launch_bounds__(256, 1) void lstm_rec_kernel(
    const float* xp,         // [TSEQ][400] permuted, includes biases
    const float* Whh,        // [400][100] original layout
    unsigned short* hs)      // [TSEQ][100] bf16
{
    __shared__ __align__(16) unsigned short h_lds[2][128];  // bf16 h, zero-padded
    __shared__ __align__(16) float preact_lds[GATES];       // per-wave-owned regions

    const int tid = threadIdx.x;
    const int lane = tid & 63;
    const int w = tid >> 6;          // wave 0..3
    const int bq = lane >> 4;        // k-block 0..3
    const int m = lane & 15;         // A row within tile / D col
    const bool writer = (m == 0);

    // ---- A fragments: 7 tile-slots (wave w: tiles 6w..6w+5; slot 6 = tile 24, w3 only)
    bf16x8 afrag[7][4];
#pragma unroll
    for (int i = 0; i < 7; ++i) {
        const int ti = (i < 6) ? (6 * w + i) : 24;
        const bool valid = (i < 6) || (w == 3);
        const int g = m & 3;                  // permuted tile-row -> gate
        const int uu = 4 * ti + (m >> 2);     // -> hidden unit
        const int orow = g * 100 + uu;        // original W_hh row
#pragma unroll
        for (int kk = 0; kk < 4; ++kk) {
            float vals[8];
            if (valid && kk < 3) {
                const float4 w0 = *(const float4*)&Whh[(size_t)orow * 100 + kk * 32 + bq * 8];
                const float4 w1 = *(const float4*)&Whh[(size_t)orow * 100 + kk * 32 + bq * 8 + 4];
                vals[0] = w0.x; vals[1] = w0.y; vals[2] = w0.z; vals[3] = w0.w;
                vals[4] = w1.x; vals[5] = w1.y; vals[6] = w1.z; vals[7] = w1.w;
            } else if (valid && bq == 0) {    // kk==3: k=96..103, only 96..99 real
                const float4 w0 = *(const float4*)&Whh[(size_t)orow * 100 + 96];
                vals[0] = w0.x; vals[1] = w0.y; vals[2] = w0.z; vals[3] = w0.w;
                vals[4] = 0.f; vals[5] = 0.f; vals[6] = 0.f; vals[7] = 0.f;
            } else {
#pragma unroll
                for (int j = 0; j < 8; ++j) vals[j] = 0.f;
            }
#pragma unroll
            for (int j = 0; j < 8; ++j) afrag[i][kk][j] = (short)f2bf(vals[j]);
        }
    }

    // ---- cell-lane mapping: wave w, lane j<nunits handles unit 24w+j
    const int nunits = (w == 3) ? 28 : 24;
    const bool cell = (lane < nunits);
    const int unit = 24 * w + lane;          // valid when `cell`

    // ---- init
    if (tid < 128) { h_lds[0][tid] = 0; h_lds[1][tid] = 0; }
    float c = 0.0f;
    float4 xpv[4];
    if (cell) {
#pragma unroll
        for (int p = 0; p < 4; ++p)
            xpv[p] = *(const float4*)&xp[(size_t)p * GATES + 4 * unit];
    }
    __syncthreads();

    for (int t = 0; t < TSEQ; t += 4) {
#pragma unroll
        for (int u = 0; u < 4; ++u) {
            const int tt = t + u;
            const int cur = u & 1;           // parity of tt == parity of u

            // ---- Phase A: B fragments (h broadcast, 16B LDS reads) + MFMA
            bf16x8 bfr[4];
#pragma unroll
            for (int kk = 0; kk < 4; ++kk) {
                const uint4 braw = *(const uint4*)&h_lds[cur][kk * 32 + bq * 8];
                bfr[kk] = __builtin_bit_cast(bf16x8, braw);
            }
#pragma unroll
            for (int i = 0; i < 7; ++i) {
                const bool valid = (i < 6) || (w == 3);
                if (valid) {
                    const int ti = (i < 6) ? (6 * w + i) : 24;
                    f32x4 acc = {0.f, 0.f, 0.f, 0.f};
                    acc = __builtin_amdgcn_mfma_f32_16x16x32_bf16(afrag[i][0], bfr[0], acc, 0, 0, 0);
                    acc = __builtin_amdgcn_mfma_f32_16x16x32_bf16(afrag[i][1], bfr[1], acc, 0, 0, 0);
                    acc = __builtin_amdgcn_mfma_f32_16x16x32_bf16(afrag[i][2], bfr[2], acc, 0, 0, 0);
                    acc = __builtin_amdgcn_mfma_f32_16x16x32_bf16(afrag[i][3], bfr[3], acc, 0, 0, 0);
                    if (writer)   // rows 4bq..4bq+3 of tile ti = unit 4ti+bq's gates
                        *(f32x4*)&preact_lds[16 * ti + 4 * bq] = acc;
                }
            }

            // ---- Phase B (same wave, no barrier): intra-wave preact pass-through
            if (cell) {
                const float4 pa = *(const float4*)&preact_lds[4 * unit];
                const float4 xq = xpv[u];
                const float gi = sigm(pa.x + xq.x);
                const float gf = sigm(pa.y + xq.y);
                const float gg = tanh_fast(pa.z + xq.z);
                const float go = sigm(pa.w + xq.w);
                c = fmaf(gf, c, gi * gg);
                const float hv = go * tanh_fast(c);
                const unsigned short hb = f2bf(hv);
                h_lds[1 - cur][unit] = hb;                     // publish (after barrier)
                if (tt + 4 < TSEQ)                             // depth-4 prefetch
                    xpv[u] = *(const float4*)&xp[(size_t)(tt + 4) * GATES + 4 * unit];
                hs[(size_t)tt * HIDDEN + unit] = hb;           // fire-and-forget bf16
            }
            LDS_BARRIER();   // single barrier: h visible to all waves for step tt+1
        }
    }
}

// ---------------------------------------------------------------------------
// Kernel 3: out[t] = sigmoid(dot(hs_bf16[t], W_lin) + b_lin)
// ---------------------------------------------------------------------------
__global__ __launch_bounds__(256) void pred_kernel(
    const unsigned short* __restrict__ hs,   // [TSEQ][100] bf16
    const float* __restrict__ wlin,          // [100]
    const float* __restrict__ blin,          // [1]
    float* __restrict__ out)                 // [TSEQ]
{
    __shared__ __align__(16) float wl[HIDDEN];
    const int tid = threadIdx.x;
    if (tid < HIDDEN) wl[tid] = wlin[tid];
    __syncthreads();

    const int t = blockIdx.x * 256 + tid;
    const unsigned short* hrow = hs + (size_t)t * HIDDEN;   // 8B-aligned
    float acc = blin[0];
#pragma unroll
    for (int kk = 0; kk < 25; ++kk) {                       // 25 x uint2 = 100 bf16
        const uint2 v = *(const uint2*)&hrow[kk * 4];
        acc = fmaf(bf2f(v.x & 0xffffu), wl[kk * 4 + 0], acc);
        acc = fmaf(bf2f(v.x >> 16),     wl[kk * 4 + 1], acc);
        acc = fmaf(bf2f(v.y & 0xffffu), wl[kk * 4 + 2], acc);
        acc = fmaf(bf2f(v.y >> 16),     wl[kk * 4 + 3], acc);
    }
    out[t] = sigm(acc);
}

// ---------------------------------------------------------------------------
extern "C" void kernel_launch(void* const* d_in, const int* in_sizes, int n_in,
                              void* d_out, int out_size, void* d_ws, size_t ws_size,
                              hipStream_t stream) {
    const float* x     = (const float*)d_in[0];  // [65536,128]
    const float* W_ih  = (const float*)d_in[1];  // [400,128]
    const float* W_hh  = (const float*)d_in[2];  // [400,100]
    const float* b_ih  = (const float*)d_in[3];  // [400]
    const float* b_hh  = (const float*)d_in[4];  // [400]
    const float* W_lin = (const float*)d_in[5];  // [1,100]
    const float* b_lin = (const float*)d_in[6];  // [1]
    float* out = (float*)d_out;                  // [65536]

    float* xp = (float*)d_ws;                                  // [TSEQ*400] fp32
    unsigned short* hs = (unsigned short*)(xp + (size_t)TSEQ * GATES);  // [TSEQ*100] bf16

    xproj_kernel<<<TSEQ / 16, 256, 0, stream>>>(x, W_ih, b_ih, b_hh, xp);
    lstm_rec_kernel<<<1, 256, 0, stream>>>(xp, W_hh, hs);
    pred_kernel<<<TSEQ / 256, 256, 0, stream>>>(hs, W_lin, b_lin, out);
}